// Round 2
// baseline (1421.540 us; speedup 1.0000x reference)
//
#include <hip/hip_runtime.h>

#define BB 512
#define TT 1024
#define DX 32
#define DZ 64
#define DY 256
#define ALPHA 0.125f

// One block per batch element, 256 threads (4 waves). 2 blocks/CU.
// Thread tid owns hidden[y=tid] (W2 row, 64 floats in arch VGPRs) and the
// partial of z_new[z=tid&63] over y-chunk g=tid>>6 (W1 slice, 64 floats in
// arch VGPRs). asm "+v" pins stop the compiler from demoting the weight
// arrays to AGPRs (R1: VGPR_Count=80 proved demotion; accvgpr_read doubled
// VALU issue). 4 accumulators break the 64-FMA dependent chain.
__global__ __launch_bounds__(256, 2)
void plrnn_scan(const float* __restrict__ X, const float* __restrict__ A,
                const float* __restrict__ W1, const float* __restrict__ W2,
                const float* __restrict__ h1, const float* __restrict__ h2,
                float* __restrict__ out) {
    const int b   = blockIdx.x;
    const int tid = threadIdx.x;
    const int z   = tid & 63;
    const int g   = tid >> 6;

    __shared__ float zf_s[DZ];
    __shared__ float hid_s[DY];
    __shared__ float part_s[256];

    // --- stage weights into registers (one-time) ---
    float4 w2[16];  // W2[y=tid][0..63]
    float4 w1[16];  // W1[z][g*64 .. g*64+63]
    const float4* W2v = (const float4*)(W2 + tid * DZ);
    const float4* W1v = (const float4*)(W1 + z * DY + g * 64);
#pragma unroll
    for (int i = 0; i < 16; ++i) w2[i] = W2v[i];
#pragma unroll
    for (int i = 0; i < 16; ++i) w1[i] = W1v[i];
    // Pin every weight component in an arch VGPR (defeat AGPR demotion /
    // load rematerialization).
#pragma unroll
    for (int i = 0; i < 16; ++i) {
        asm volatile("" : "+v"(w2[i].x), "+v"(w2[i].y), "+v"(w2[i].z), "+v"(w2[i].w));
        asm volatile("" : "+v"(w1[i].x), "+v"(w1[i].y), "+v"(w1[i].z), "+v"(w1[i].w));
    }

    const float h2r = h2[tid];
    const float Ar  = A[z];
    const float h1r = h1[z];

    const float* Xb = X   + (size_t)b * TT * DX;
    float*       Ob = out + (size_t)b * TT * DX;

    // --- zf for t=0: tf(zeros, X0, 1.0) then tf(z0, X0, 0.125) == z0 ---
    float zfreg = 0.0f;  // updater threads (tid<64) carry zf across steps
    if (tid < DZ) {
        float zf = 0.0f;
        if (z < DX) {
            float x0 = Xb[z];
            zf = (x0 == x0) ? x0 : 0.0f;
        }
        zfreg = zf;
        zf_s[z] = zf;
    }
    __syncthreads();

    for (int t = 0; t < TT; ++t) {
        // prefetch next forcing value (consumed at loop tail by updater)
        float xnext = 0.0f;
        if (tid < DX && t + 1 < TT) xnext = Xb[(t + 1) * DX + tid];

        // hidden[y=tid] = relu(W2[y] . zf + h2[y]); 4 independent chains
        const float4* zf4 = (const float4*)zf_s;
        float a0 = h2r, a1 = 0.0f, a2 = 0.0f, a3 = 0.0f;
#pragma unroll
        for (int i = 0; i < 16; i += 4) {
            float4 v0 = zf4[i + 0];
            float4 v1 = zf4[i + 1];
            float4 v2 = zf4[i + 2];
            float4 v3 = zf4[i + 3];
            a0 = fmaf(w2[i + 0].x, v0.x, a0); a0 = fmaf(w2[i + 0].y, v0.y, a0);
            a0 = fmaf(w2[i + 0].z, v0.z, a0); a0 = fmaf(w2[i + 0].w, v0.w, a0);
            a1 = fmaf(w2[i + 1].x, v1.x, a1); a1 = fmaf(w2[i + 1].y, v1.y, a1);
            a1 = fmaf(w2[i + 1].z, v1.z, a1); a1 = fmaf(w2[i + 1].w, v1.w, a1);
            a2 = fmaf(w2[i + 2].x, v2.x, a2); a2 = fmaf(w2[i + 2].y, v2.y, a2);
            a2 = fmaf(w2[i + 2].z, v2.z, a2); a2 = fmaf(w2[i + 2].w, v2.w, a2);
            a3 = fmaf(w2[i + 3].x, v3.x, a3); a3 = fmaf(w2[i + 3].y, v3.y, a3);
            a3 = fmaf(w2[i + 3].z, v3.z, a3); a3 = fmaf(w2[i + 3].w, v3.w, a3);
        }
        hid_s[tid] = fmaxf((a0 + a1) + (a2 + a3), 0.0f);
        __syncthreads();

        // partial of z_new[z] over y-chunk g; 4 independent chains
        const float4* h4 = (const float4*)(hid_s + g * 64);
        float p0 = 0.0f, p1 = 0.0f, p2 = 0.0f, p3 = 0.0f;
#pragma unroll
        for (int i = 0; i < 16; i += 4) {
            float4 v0 = h4[i + 0];
            float4 v1 = h4[i + 1];
            float4 v2 = h4[i + 2];
            float4 v3 = h4[i + 3];
            p0 = fmaf(w1[i + 0].x, v0.x, p0); p0 = fmaf(w1[i + 0].y, v0.y, p0);
            p0 = fmaf(w1[i + 0].z, v0.z, p0); p0 = fmaf(w1[i + 0].w, v0.w, p0);
            p1 = fmaf(w1[i + 1].x, v1.x, p1); p1 = fmaf(w1[i + 1].y, v1.y, p1);
            p1 = fmaf(w1[i + 1].z, v1.z, p1); p1 = fmaf(w1[i + 1].w, v1.w, p1);
            p2 = fmaf(w1[i + 2].x, v2.x, p2); p2 = fmaf(w1[i + 2].y, v2.y, p2);
            p2 = fmaf(w1[i + 2].z, v2.z, p2); p2 = fmaf(w1[i + 2].w, v2.w, p2);
            p3 = fmaf(w1[i + 3].x, v3.x, p3); p3 = fmaf(w1[i + 3].y, v3.y, p3);
            p3 = fmaf(w1[i + 3].z, v3.z, p3); p3 = fmaf(w1[i + 3].w, v3.w, p3);
        }
        part_s[tid] = (p0 + p1) + (p2 + p3);
        __syncthreads();

        // updater: finish z_new, emit output, prepare zf for t+1
        if (tid < DZ) {
            float s = (part_s[z] + part_s[z + 64]) + (part_s[z + 128] + part_s[z + 192]);
            float znew = fmaf(Ar, zfreg, s + h1r);
            float zf = znew;
            if (z < DX) {
                Ob[t * DX + z] = znew;
                float f = xnext;
                zf = (f == f) ? fmaf(ALPHA, f, (1.0f - ALPHA) * znew) : znew;
            }
            zfreg = zf;
            zf_s[z] = zf;
        }
        __syncthreads();
    }
}

extern "C" void kernel_launch(void* const* d_in, const int* in_sizes, int n_in,
                              void* d_out, int out_size, void* d_ws, size_t ws_size,
                              hipStream_t stream) {
    const float* X  = (const float*)d_in[0];
    const float* A  = (const float*)d_in[1];
    const float* W1 = (const float*)d_in[2];
    const float* W2 = (const float*)d_in[3];
    const float* h1 = (const float*)d_in[4];
    const float* h2 = (const float*)d_in[5];
    float* out = (float*)d_out;

    plrnn_scan<<<BB, 256, 0, stream>>>(X, A, W1, W2, h1, h2, out);
}

// Round 3
// 890.538 us; speedup vs baseline: 1.5963x; 1.5963x over previous
//
#include <hip/hip_runtime.h>

#define BB 512
#define TT 1024
#define DX 32
#define DZ 64
#define DY 256
#define ALPHA 0.125f

// quad_perm DPP add: x + permuted(x) within each 4-lane quad (VALU pipe, no LDS).
// 0xB1 = quad_perm[1,0,3,2] (xor 1), 0x4E = quad_perm[2,3,0,1] (xor 2).
template<int CTRL>
__device__ __forceinline__ float qperm_add(float x) {
    int p = __builtin_amdgcn_update_dpp(0, __float_as_int(x), CTRL, 0xF, 0xF, true);
    return x + __int_as_float(p);
}
__device__ __forceinline__ float quad_allreduce(float x) {
    x = qperm_add<0xB1>(x);
    x = qperm_add<0x4E>(x);
    return x;
}

// One block per batch element, 256 threads (4 waves), 2 blocks/CU.
// m1: thread (j=tid>>2, s=tid&3): hidden y-block 4j..4j+3 over z-slice 16s..16s+15.
//     Quad (same j, s=0..3) holds all 4 z-slices -> quad_perm butterfly completes
//     the dot product in-register (no partial LDS round-trip).
// m2: thread (p=(tid>>2)&15, c=tid&3, w=tid>>6): z-block 4p..4p+3 over y-slice
//     16*(4w+c).. ; quad butterfly sums 4 y-slices (64 y per wave), one b128
//     partial write per wave, updater wave reduces the 4 wave-partials.
__global__ __launch_bounds__(256, 2)
void plrnn_scan(const float* __restrict__ X, const float* __restrict__ A,
                const float* __restrict__ W1, const float* __restrict__ W2,
                const float* __restrict__ h1, const float* __restrict__ h2,
                float* __restrict__ out) {
    const int b   = blockIdx.x;
    const int tid = threadIdx.x;

    const int j  = tid >> 2;        // 0..63  (m1 y-block)
    const int s  = tid & 3;         // 0..3   (m1 z-slice / quad lane)
    const int p  = (tid >> 2) & 15; // 0..15  (m2 z-block)
    const int c  = tid & 3;         // 0..3   (m2 y-subslice / quad lane)
    const int wv = tid >> 6;        // 0..3   (wave id)
    const int s2 = (wv << 2) | c;   // 0..15  (m2 y-slice)

    __shared__ float zf_s[DZ];
    __shared__ float hid_s[DY];
    __shared__ float part_s[4 * 68];  // 4 wave-rows, pad 64->68 for bank spread

    // ---- one-time: stage weight tiles into registers ----
    float4 w2c[16];  // w2c[k].r = W2[(4j+r)*64 + 16s+k]
    float4 w1c[16];  // w1c[k].r = W1[(4p+r)*256 + 16*s2+k]
#pragma unroll
    for (int k = 0; k < 16; ++k) {
        w2c[k] = make_float4(W2[(4 * j + 0) * DZ + 16 * s + k],
                             W2[(4 * j + 1) * DZ + 16 * s + k],
                             W2[(4 * j + 2) * DZ + 16 * s + k],
                             W2[(4 * j + 3) * DZ + 16 * s + k]);
        w1c[k] = make_float4(W1[(4 * p + 0) * DY + 16 * s2 + k],
                             W1[(4 * p + 1) * DY + 16 * s2 + k],
                             W1[(4 * p + 2) * DY + 16 * s2 + k],
                             W1[(4 * p + 3) * DY + 16 * s2 + k]);
    }
    const float4 h2q = make_float4(h2[4 * j + 0], h2[4 * j + 1],
                                   h2[4 * j + 2], h2[4 * j + 3]);
    const float Ar  = (tid < DZ) ? A[tid]  : 0.0f;
    const float h1r = (tid < DZ) ? h1[tid] : 0.0f;

    const float* Xb = X   + (size_t)b * TT * DX;
    float*       Ob = out + (size_t)b * TT * DX;

    // ---- zf_0: tf(zeros, X0, 1.0) then tf(z0, X0, 0.125) == x0 (non-NaN) ----
    float zfreg = 0.0f;
    if (tid < DZ) {
        float zf = 0.0f;
        if (tid < DX) { float x0 = Xb[tid]; zf = (x0 == x0) ? x0 : 0.0f; }
        zfreg = zf;
        zf_s[tid] = zf;
    }
    __syncthreads();

    for (int t = 0; t < TT; ++t) {
        // prefetch next forcing value early (consumed by updater at loop tail)
        float xnext = 0.0f;
        if (tid < DX && (t + 1) < TT) xnext = Xb[(t + 1) * DX + tid];

        // ---- m1: hidden = relu(W2 @ zf + h2) ----
        float zl[16];
        {
            const float4* zp = (const float4*)zf_s + 4 * s;
            *(float4*)&zl[0]  = zp[0];
            *(float4*)&zl[4]  = zp[1];
            *(float4*)&zl[8]  = zp[2];
            *(float4*)&zl[12] = zp[3];
        }
        float ax = 0.f, ay = 0.f, az = 0.f, aw = 0.f;
#pragma unroll
        for (int k = 0; k < 16; ++k) {
            ax = fmaf(w2c[k].x, zl[k], ax);
            ay = fmaf(w2c[k].y, zl[k], ay);
            az = fmaf(w2c[k].z, zl[k], az);
            aw = fmaf(w2c[k].w, zl[k], aw);
        }
        ax = quad_allreduce(ax);
        ay = quad_allreduce(ay);
        az = quad_allreduce(az);
        aw = quad_allreduce(aw);
        if (s == 0) {
            float4 hv = make_float4(fmaxf(ax + h2q.x, 0.f), fmaxf(ay + h2q.y, 0.f),
                                    fmaxf(az + h2q.z, 0.f), fmaxf(aw + h2q.w, 0.f));
            *(float4*)&hid_s[4 * j] = hv;
        }
        __syncthreads();

        // ---- m2: z_partial = W1 @ hidden ----
        float hl[16];
        {
            const float4* hp = (const float4*)hid_s + 4 * s2;
            *(float4*)&hl[0]  = hp[0];
            *(float4*)&hl[4]  = hp[1];
            *(float4*)&hl[8]  = hp[2];
            *(float4*)&hl[12] = hp[3];
        }
        float px = 0.f, py = 0.f, pz = 0.f, pw = 0.f;
#pragma unroll
        for (int k = 0; k < 16; ++k) {
            px = fmaf(w1c[k].x, hl[k], px);
            py = fmaf(w1c[k].y, hl[k], py);
            pz = fmaf(w1c[k].z, hl[k], pz);
            pw = fmaf(w1c[k].w, hl[k], pw);
        }
        px = quad_allreduce(px);
        py = quad_allreduce(py);
        pz = quad_allreduce(pz);
        pw = quad_allreduce(pw);
        if (c == 0) {
            *(float4*)&part_s[wv * 68 + 4 * p] = make_float4(px, py, pz, pw);
        }
        __syncthreads();

        // ---- update (wave 0 only): z_new = A*zf + sum(partials) + h1 ----
        if (tid < DZ) {
            float ssum = (part_s[tid] + part_s[68 + tid]) +
                         (part_s[136 + tid] + part_s[204 + tid]);
            float znew = fmaf(Ar, zfreg, ssum + h1r);
            float zf = znew;
            if (tid < DX) {
                Ob[t * DX + tid] = znew;
                zf = (xnext == xnext) ? fmaf(ALPHA, xnext, (1.0f - ALPHA) * znew)
                                      : znew;
            }
            zfreg = zf;
            zf_s[tid] = zf;
        }
        __syncthreads();
    }
}

extern "C" void kernel_launch(void* const* d_in, const int* in_sizes, int n_in,
                              void* d_out, int out_size, void* d_ws, size_t ws_size,
                              hipStream_t stream) {
    const float* X  = (const float*)d_in[0];
    const float* A  = (const float*)d_in[1];
    const float* W1 = (const float*)d_in[2];
    const float* W2 = (const float*)d_in[3];
    const float* h1 = (const float*)d_in[4];
    const float* h2 = (const float*)d_in[5];
    float* out = (float*)d_out;

    plrnn_scan<<<BB, 256, 0, stream>>>(X, A, W1, W2, h1, h2, out);
}